// Round 7
// baseline (520.260 us; speedup 1.0000x reference)
//
#include <hip/hip_runtime.h>
#include <math.h>

#define BB 32
#define SS 2048
#define DD 512
#define AD 512

#define BM 128
#define BN 128
#define BK 64    // K elems per chunk. A row: 64 fp32 = 256 B = 16 granules;
                 // B row: 64 bf16 = 128 B = 8 granules (granule = 16 B)

typedef __bf16 bf16;
typedef __attribute__((ext_vector_type(8))) __bf16 bf16x8;
typedef __attribute__((ext_vector_type(4))) __bf16 bf16x4;
typedef __attribute__((ext_vector_type(4))) float floatx4;

__device__ inline void async16(const void* g, void* l) {
    __builtin_amdgcn_global_load_lds(
        (const __attribute__((address_space(1))) unsigned int*)g,
        (__attribute__((address_space(3))) unsigned int*)l, 16, 0, 0);
}

// ---------------- K1: fused prep ----------------
// blocks [0, NCV)                  : fp32->bf16 convert of W2 (1 MB only)
// blocks [NCV, NCV+64)             : mask dtype probe -> flag (for softmax)
// blocks [NCV+64, NCV+64+4096)     : w1q[b][a] = dot(query[b,:], W1[a,:])
// blocks [NCV+64+4096, +32)        : per-batch mask compaction -> idx, cnt
#define NW8 (AD * DD / 8)
#define NCV (NW8 / 256)   // 128
__global__ void prep_kernel(const float* __restrict__ W2,
                            bf16* __restrict__ W2b,
                            const unsigned char* __restrict__ m8,
                            int* __restrict__ flag,
                            const float* __restrict__ query,
                            const float* __restrict__ W1,
                            float* __restrict__ w1q,
                            int* __restrict__ cnt,
                            int* __restrict__ idxb) {
    const int bid = blockIdx.x;
    if (bid < NCV) {
        int j = threadIdx.x + bid * 256;
        const float4* s4 = (const float4*)W2 + (size_t)j * 2;
        float4 x = s4[0], y = s4[1];
        bf16x8 o;
        o[0] = (bf16)x.x; o[1] = (bf16)x.y; o[2] = (bf16)x.z; o[3] = (bf16)x.w;
        o[4] = (bf16)y.x; o[5] = (bf16)y.y; o[6] = (bf16)y.z; o[7] = (bf16)y.w;
        *(bf16x8*)(W2b + (size_t)j * 8) = o;
    } else if (bid < NCV + 64) {
        int t = threadIdx.x + (bid - NCV) * 256;
        int any = 0;
        for (int i = t; i < BB * SS; i += 64 * 256)
            if ((i & 3) && m8[i]) any = 1;
        if (__any(any)) {
            if ((threadIdx.x & 63) == 0) atomicOr(flag, 1);
        }
    } else if (bid < NCV + 64 + 4096) {
        int id = bid - NCV - 64;           // 0..4095
        int b = id >> 7;
        int a = (id & 127) * 4 + (threadIdx.x >> 6);
        int lane = threadIdx.x & 63;
        const float4* q4 = (const float4*)(query + (size_t)b * DD) + lane * 2;
        const float4* w4 = (const float4*)(W1 + (size_t)a * DD) + lane * 2;
        float4 qa = q4[0], qb = q4[1];
        float4 wa = w4[0], wb = w4[1];
        float acc = qa.x * wa.x + qa.y * wa.y + qa.z * wa.z + qa.w * wa.w
                  + qb.x * wb.x + qb.y * wb.y + qb.z * wb.z + qb.w * wb.w;
#pragma unroll
        for (int off = 32; off > 0; off >>= 1) acc += __shfl_down(acc, off);
        if (lane == 0) w1q[(size_t)b * AD + a] = acc;
    } else {
        // ---- compaction: one block per batch ----
        const int b = bid - NCV - 64 - 4096;   // 0..31
        const int t = threadIdx.x;
        const int lane = t & 63, wid = t >> 6;
        __shared__ int s_base;
        __shared__ int wsum[4];
        __shared__ int s_bytes;
        if (t == 0) { s_base = 0; s_bytes = 0; }
        __syncthreads();
        // local dtype probe on first 2048 bytes (valid for either dtype):
        // i32 mask entries are 0/1 -> bytes %4!=0 all zero; u8 mask has
        // ~1024 nonzero bytes there -> decision error prob ~2^-1500.
        {
            const unsigned* mu = (const unsigned*)m8;
            unsigned pr = (mu[t] | mu[t + 256]) & 0xFFFFFF00u;
            if (pr) atomicOr(&s_bytes, 1);
        }
        __syncthreads();
        const int bytes = s_bytes;
        const int* m32 = (const int*)m8;
#pragma unroll 1
        for (int c = 0; c < 8; ++c) {
            int s = c * 256 + t;
            int mv = bytes ? (int)m8[(size_t)b * SS + s]
                           : m32[(size_t)b * SS + s];
            unsigned long long ball = __ballot(mv != 0);
            int rank = __popcll(ball & ((1ull << lane) - 1ull));
            if (lane == 0) wsum[wid] = __popcll(ball);
            __syncthreads();
            int woff = s_base;
            for (int j = 0; j < wid; ++j) woff += wsum[j];
            if (mv) idxb[(size_t)b * SS + woff + rank] = s;
            __syncthreads();
            if (t == 0) s_base += wsum[0] + wsum[1] + wsum[2] + wsum[3];
            __syncthreads();
        }
        if (t == 0) cnt[b] = s_base;
    }
}

// ---------------- K2: gathered MFMA GEMM + tanh/v + FUSED softmax ---------
// Round-0 compute structure + row-gather (round-6, verified). NEW: the
// last active block per batch (device-scope completion counter) runs the
// per-batch masked softmax inline, eliminating the K3 dispatch. Fence+
// atomic pattern per Guidelines 12/16 (XCD-safe; no ordering assumption).
__global__ __launch_bounds__(256, 3)
void gemm_scores_mfma(const float* __restrict__ keys,
                      const bf16* __restrict__ W2b,
                      const float* __restrict__ w1q,
                      const float* __restrict__ v,
                      const int* __restrict__ cnt,
                      const int* __restrict__ idxb,
                      float* __restrict__ partial,
                      const int* __restrict__ mask_i32,
                      const unsigned char* __restrict__ mask_u8,
                      const int* __restrict__ flag,
                      int* __restrict__ bcnt,
                      float* __restrict__ out) {
    __shared__ float a_lds[BM * BK];   // 32 KB fp32
    __shared__ bf16  b_lds[BN * BK];   // 16 KB bf16
    __shared__ int   idx_lds[BM];      // 512 B
    __shared__ float rmax[4], rsum[4];
    __shared__ int   s_last;

    const int t    = threadIdx.x;
    const int lane = t & 63;
    const int w    = t >> 6;
    const int ml   = lane & 15;
    const int kg   = lane >> 4;

    // grid decode: lin -> (keys-tile kt, a_tile) with lin&7 == kt&7 (XCD)
    const int lin    = blockIdx.x;
    const int x8     = lin & 7;
    const int hi     = lin >> 3;
    const int a_tile = hi & 3;
    const int kt     = x8 + ((hi >> 2) << 3);   // 0..511
    const int b      = kt >> 4;
    const int s0     = (kt & 15) * BM;
    const int a0     = a_tile * BN;

    const int cntb = cnt[b];
    if (s0 >= cntb) return;            // whole tile masked out -> no work

    const int m_off = (w & 1) * 64;
    const int n_off = (w >> 1) * 64;

    const float* Akeys = keys + (size_t)b * SS * DD;
    const bf16*  Bblk  = W2b + (size_t)a0 * DD;

    // stage the idx tile (clamped; cntb >= 1 here)
    if (t < BM) {
        int p = s0 + t;
        idx_lds[t] = idxb[(size_t)b * SS + (p < cntb ? p : cntb - 1)];
    }
    __syncthreads();

    // hoist the 8 per-thread A-row gathers (rows are chunk-invariant)
    int arow[8];
#pragma unroll
    for (int i = 0; i < 8; ++i) arow[i] = idx_lds[(t + 256 * i) >> 4];

    floatx4 acc[4][4];
#pragma unroll
    for (int mi = 0; mi < 4; ++mi)
#pragma unroll
        for (int ni = 0; ni < 4; ++ni)
            acc[mi][ni] = (floatx4)(0.f);

    const int NCHUNK = DD / BK;   // 8
    for (int c = 0; c < NCHUNK; ++c) {
        const int d0 = c * BK;
        __syncthreads();   // previous chunk's frag reads done
        // A: 2048 granules (16B = 4 fp32), 8 per thread, row-gathered
#pragma unroll
        for (int i = 0; i < 8; ++i) {
            int g = t + 256 * i;
            int r = g >> 4, cc = g & 15, cs = cc ^ (r & 15);
            async16(Akeys + (size_t)arow[i] * DD + d0 + cs * 4,
                    &a_lds[(256 * i + 64 * w) * 4]);
        }
        // B: 1024 granules (16B = 8 bf16), 4 per thread
#pragma unroll
        for (int i = 0; i < 4; ++i) {
            int g = t + 256 * i;
            int r = g >> 3, cc = g & 7, cs = cc ^ (r & 7);
            async16(Bblk + (size_t)r * DD + d0 + cs * 8,
                    &b_lds[(256 * i + 64 * w) * 8]);
        }
        __syncthreads();   // staging drained

#pragma unroll
        for (int ks = 0; ks < 2; ++ks) {
            bf16x8 af[4], bfr[4];
#pragma unroll
            for (int mi = 0; mi < 4; ++mi) {
                int R  = m_off + mi * 16 + ml;
                int gB = 8 * ks + 2 * kg;           // even
                float4 lo = *(const float4*)&a_lds[R * BK + ((gB    ) ^ (R & 15)) * 4];
                float4 hi4 = *(const float4*)&a_lds[R * BK + ((gB + 1) ^ (R & 15)) * 4];
                bf16x8 f;
                f[0] = (bf16)lo.x;  f[1] = (bf16)lo.y;
                f[2] = (bf16)lo.z;  f[3] = (bf16)lo.w;
                f[4] = (bf16)hi4.x; f[5] = (bf16)hi4.y;
                f[6] = (bf16)hi4.z; f[7] = (bf16)hi4.w;
                af[mi] = f;
            }
#pragma unroll
            for (int ni = 0; ni < 4; ++ni) {
                int R = n_off + ni * 16 + ml;
                int pos = (ks * 4 + kg) ^ (R & 7);
                bfr[ni] = *(const bf16x8*)&b_lds[R * BK + pos * 8];
            }
#pragma unroll
            for (int mi = 0; mi < 4; ++mi)
#pragma unroll
                for (int ni = 0; ni < 4; ++ni)
                    acc[mi][ni] = __builtin_amdgcn_mfma_f32_16x16x32_bf16(
                        af[mi], bfr[ni], acc[mi][ni], 0, 0, 0);
        }
    }

    // epilogue: tanh + v-weight; quad shuffle-reduce over 64 a's; scatter
    // store to partial[(b, idx[row])*8 + a_tile*2 + n_half], rows < cntb.
    float w1qa[4], va[4];
#pragma unroll
    for (int ni = 0; ni < 4; ++ni) {
        int a = a0 + n_off + ni * 16 + ml;
        w1qa[ni] = w1q[(size_t)b * AD + a];
        va[ni]   = v[a];
    }
    const int slot = a_tile * 2 + (w >> 1);
#pragma unroll
    for (int mi = 0; mi < 4; ++mi) {
#pragma unroll
        for (int reg = 0; reg < 4; ++reg) {
            float p = 0.f;
#pragma unroll
            for (int ni = 0; ni < 4; ++ni) {
                float x = acc[mi][ni][reg] + w1qa[ni];
                float th = 1.f - 2.f / (1.f + __expf(2.f * x));
                p = fmaf(th, va[ni], p);
            }
            p += __shfl_xor(p, 1);
            p += __shfl_xor(p, 2);
            p += __shfl_xor(p, 4);
            p += __shfl_xor(p, 8);
            int row = m_off + mi * 16 + kg * 4 + reg;
            if (ml == 0 && s0 + row < cntb) {
                int os = idx_lds[row];
                partial[((size_t)b * SS + os) * 8 + slot] = p;
            }
        }
    }

    // ---- fused completion: last active block for batch b does softmax ----
    __threadfence();                    // release our partial stores
    if (t == 0) {
        const int nact = 4 * ((cntb + BM - 1) / BM);
        int old = atomicAdd(&bcnt[b], 1);
        s_last = (old == nact - 1);
    }
    __syncthreads();
    if (!s_last) return;
    __threadfence();                    // acquire all blocks' partial stores

    {
        const int wid = w;
        const int bytes = (*flag != 0);
        float sv[8]; int mv[8];
#pragma unroll
        for (int k = 0; k < 8; ++k) {
            int i = t + 256 * k;
            const float4* p4 = (const float4*)(partial + ((size_t)b * SS + i) * 8);
            float4 pa = p4[0], pb = p4[1];
            sv[k] = ((pa.x + pa.y) + (pa.z + pa.w)) + ((pb.x + pb.y) + (pb.z + pb.w));
            mv[k] = bytes ? (int)mask_u8[(size_t)b * SS + i]
                          : mask_i32[(size_t)b * SS + i];
        }

        float mx = -INFINITY;
#pragma unroll
        for (int k = 0; k < 8; ++k) mx = fmaxf(mx, mv[k] ? sv[k] : -INFINITY);
#pragma unroll
        for (int off = 32; off > 0; off >>= 1) mx = fmaxf(mx, __shfl_xor(mx, off));
        if (lane == 0) rmax[wid] = mx;
        __syncthreads();
        mx = fmaxf(fmaxf(rmax[0], rmax[1]), fmaxf(rmax[2], rmax[3]));

        float ev[8]; float sum = 0.f;
#pragma unroll
        for (int k = 0; k < 8; ++k) {
            ev[k] = mv[k] ? __expf(sv[k] - mx) : 0.f;
            sum += ev[k];
        }
#pragma unroll
        for (int off = 32; off > 0; off >>= 1) sum += __shfl_xor(sum, off);
        if (lane == 0) rsum[wid] = sum;
        __syncthreads();
        sum = (rsum[0] + rsum[1]) + (rsum[2] + rsum[3]);
        float inv = 1.f / sum;
#pragma unroll
        for (int k = 0; k < 8; ++k)
            out[(size_t)b * SS + t + 256 * k] = ev[k] * inv;
    }
}

// ---------------- K2-fallback (round-0 verbatim, no gather) ---------------
#define FBK 32
#define FLDK (FBK + 8)
__global__ __launch_bounds__(256, 2)
void gemm_scores_fallback(const float* __restrict__ keys,
                          const float* __restrict__ W2,
                          const float* __restrict__ w1q,
                          const float* __restrict__ v,
                          float* __restrict__ partial) {
    __shared__ bf16 a_lds[BM][FLDK];
    __shared__ bf16 b_lds[BN][FLDK];
    __shared__ float s_red[BM];

    const int t    = threadIdx.x;
    const int lane = t & 63;
    const int w    = t >> 6;
    const int ml   = lane & 15;
    const int kg   = lane >> 4;
    const int b    = blockIdx.z;
    const int s0   = blockIdx.x * BM;
    const int a0   = blockIdx.y * BN;
    const int m_off = (w & 1) * 64;
    const int n_off = (w >> 1) * 64;

    const float* Ablk = keys + ((size_t)b * SS + s0) * DD;
    const float* Bblk = W2 + (size_t)a0 * DD;

    if (t < BM) s_red[t] = 0.f;

    floatx4 acc[4][4];
#pragma unroll
    for (int mi = 0; mi < 4; ++mi)
#pragma unroll
        for (int ni = 0; ni < 4; ++ni)
            acc[mi][ni] = (floatx4)(0.f);

    float4 ga[4], gb[4];
#pragma unroll
    for (int i = 0; i < 4; ++i) {
        int idx = t + 256 * i;
        int r = idx >> 3, c = idx & 7;
        ga[i] = *(const float4*)(Ablk + (size_t)r * DD + c * 4);
        gb[i] = *(const float4*)(Bblk + (size_t)r * DD + c * 4);
    }

    for (int chunk = 0; chunk < DD / FBK; ++chunk) {
        __syncthreads();
#pragma unroll
        for (int i = 0; i < 4; ++i) {
            int idx = t + 256 * i;
            int r = idx >> 3, c = idx & 7;
            bf16x4 pa, pb;
            pa[0] = (bf16)ga[i].x; pa[1] = (bf16)ga[i].y;
            pa[2] = (bf16)ga[i].z; pa[3] = (bf16)ga[i].w;
            pb[0] = (bf16)gb[i].x; pb[1] = (bf16)gb[i].y;
            pb[2] = (bf16)gb[i].z; pb[3] = (bf16)gb[i].w;
            *(bf16x4*)&a_lds[r][c * 4] = pa;
            *(bf16x4*)&b_lds[r][c * 4] = pb;
        }
        __syncthreads();
        if (chunk < DD / FBK - 1) {
            int d0 = (chunk + 1) * FBK;
#pragma unroll
            for (int i = 0; i < 4; ++i) {
                int idx = t + 256 * i;
                int r = idx >> 3, c = idx & 7;
                ga[i] = *(const float4*)(Ablk + (size_t)r * DD + d0 + c * 4);
                gb[i] = *(const float4*)(Bblk + (size_t)r * DD + d0 + c * 4);
            }
        }
        bf16x8 af[4], bfr[4];
#pragma unroll
        for (int mi = 0; mi < 4; ++mi)
            af[mi] = *(const bf16x8*)&a_lds[m_off + mi * 16 + ml][kg * 8];
#pragma unroll
        for (int ni = 0; ni < 4; ++ni)
            bfr[ni] = *(const bf16x8*)&b_lds[n_off + ni * 16 + ml][kg * 8];
#pragma unroll
        for (int mi = 0; mi < 4; ++mi)
#pragma unroll
            for (int ni = 0; ni < 4; ++ni)
                acc[mi][ni] = __builtin_amdgcn_mfma_f32_16x16x32_bf16(
                    af[mi], bfr[ni], acc[mi][ni], 0, 0, 0);
    }

    float w1qa[4], va[4];
#pragma unroll
    for (int ni = 0; ni < 4; ++ni) {
        int a = a0 + n_off + ni * 16 + ml;
        w1qa[ni] = w1q[(size_t)b * AD + a];
        va[ni]   = v[a];
    }
#pragma unroll
    for (int mi = 0; mi < 4; ++mi) {
#pragma unroll
        for (int reg = 0; reg < 4; ++reg) {
            float p = 0.f;
#pragma unroll
            for (int ni = 0; ni < 4; ++ni) {
                float x = acc[mi][ni][reg] + w1qa[ni];
                float th = 1.f - 2.f / (1.f + __expf(2.f * x));
                p = fmaf(th, va[ni], p);
            }
            p += __shfl_xor(p, 1);
            p += __shfl_xor(p, 2);
            p += __shfl_xor(p, 4);
            p += __shfl_xor(p, 8);
            if (ml == 0)
                atomicAdd(&s_red[m_off + mi * 16 + kg * 4 + reg], p);
        }
    }
    __syncthreads();
    if (t < BM)
        partial[(((size_t)b * SS) + s0 + t) * 8 + blockIdx.y * 2] = s_red[t];
}

// ---------------- K3: standalone softmax (fallback path only) -------------
__global__ void softmax_kernel(const float* __restrict__ partial,
                               const int* __restrict__ mask_i32,
                               const unsigned char* __restrict__ mask_u8,
                               const int* __restrict__ flag,
                               float* __restrict__ out) {
    const int b = blockIdx.x;
    const int t = threadIdx.x;
    __shared__ float rmax[4], rsum[4];
    const int wid = t >> 6, lane = t & 63;

    float sv[8]; int mv[8];
    const int bytes = (*flag != 0);
#pragma unroll
    for (int k = 0; k < 8; ++k) {
        int i = t + 256 * k;
        const float4* p4 = (const float4*)(partial + ((size_t)b * SS + i) * 8);
        float4 pa = p4[0], pb = p4[1];
        sv[k] = ((pa.x + pa.y) + (pa.z + pa.w)) + ((pb.x + pb.y) + (pb.z + pb.w));
        mv[k] = bytes ? (int)mask_u8[(size_t)b * SS + i]
                      : mask_i32[(size_t)b * SS + i];
    }

    float mx = -INFINITY;
#pragma unroll
    for (int k = 0; k < 8; ++k) mx = fmaxf(mx, mv[k] ? sv[k] : -INFINITY);
#pragma unroll
    for (int off = 32; off > 0; off >>= 1) mx = fmaxf(mx, __shfl_xor(mx, off));
    if (lane == 0) rmax[wid] = mx;
    __syncthreads();
    mx = fmaxf(fmaxf(rmax[0], rmax[1]), fmaxf(rmax[2], rmax[3]));

    float ev[8]; float sum = 0.f;
#pragma unroll
    for (int k = 0; k < 8; ++k) {
        ev[k] = mv[k] ? __expf(sv[k] - mx) : 0.f;
        sum += ev[k];
    }
#pragma unroll
    for (int off = 32; off > 0; off >>= 1) sum += __shfl_xor(sum, off);
    if (lane == 0) rsum[wid] = sum;
    __syncthreads();
    sum = (rsum[0] + rsum[1]) + (rsum[2] + rsum[3]);
    float inv = 1.f / sum;
#pragma unroll
    for (int k = 0; k < 8; ++k)
        out[(size_t)b * SS + t + 256 * k] = ev[k] * inv;
}

extern "C" void kernel_launch(void* const* d_in, const int* in_sizes, int n_in,
                              void* d_out, int out_size, void* d_ws, size_t ws_size,
                              hipStream_t stream) {
    const float* query = (const float*)d_in[0];
    const float* keys  = (const float*)d_in[1];
    const void*  mask  = d_in[2];
    const float* W1    = (const float*)d_in[3];
    const float* W2    = (const float*)d_in[4];
    const float* v     = (const float*)d_in[5];
    float* out = (float*)d_out;

    // ws layout (bytes):
    // [flag 4 @0 | bcnt[32] @64 | pad to 256][w1q 64K][partial 2M]
    // [W2b 0.5M][cnt 256][idx 256K]
    char* wsb = (char*)d_ws;
    int*   flag    = (int*)wsb;
    int*   bcnt    = (int*)(wsb + 64);
    float* w1q     = (float*)(wsb + 256);
    float* partial = (float*)(wsb + 256 + 65536);
    bf16*  W2b     = (bf16*)(wsb + 256 + 65536 + 2097152);
    int*   cnt     = (int*)(wsb + 256 + 65536 + 2097152 + 524288);
    int*   idxb    = (int*)(wsb + 256 + 65536 + 2097152 + 524288 + 256);
    size_t need = 256 + 65536 + 2097152 + 524288 + 256
                + (size_t)BB * SS * sizeof(int);

    if (ws_size >= need) {
        hipMemsetAsync(wsb, 0, 256, stream);   // flag + bcnt
        prep_kernel<<<NCV + 64 + 4096 + 32, 256, 0, stream>>>(
            W2, W2b, (const unsigned char*)mask, flag, query, W1, w1q,
            cnt, idxb);
        gemm_scores_mfma<<<(SS / BM) * (AD / BN) * BB, 256, 0, stream>>>(
            keys, W2b, w1q, v, cnt, idxb, partial,
            (const int*)mask, (const unsigned char*)mask, flag, bcnt, out);
    } else {
        hipMemsetAsync(wsb, 0, 256, stream);
        hipMemsetAsync(partial, 0, (size_t)BB * SS * 8 * 4, stream);
        prep_kernel<<<NCV + 64 + 4096, 256, 0, stream>>>(
            W2, (bf16*)(wsb + 256 + 65536 + 2097152),
            (const unsigned char*)mask, flag, query, W1, w1q,
            nullptr, nullptr);
        gemm_scores_fallback<<<dim3(SS / BM, AD / BN, BB), 256, 0, stream>>>(
            keys, W2, w1q, v, partial);
        softmax_kernel<<<BB, 256, 0, stream>>>(partial, (const int*)mask,
                                               (const unsigned char*)mask,
                                               flag, out);
    }
}

// Round 8
// 265.868 us; speedup vs baseline: 1.9568x; 1.9568x over previous
//
#include <hip/hip_runtime.h>
#include <math.h>

#define BB 32
#define SS 2048
#define DD 512
#define AD 512

#define BM 128
#define BN 128
#define BK 64    // K elems per chunk. A row: 64 fp32 = 256 B = 16 granules;
                 // B row: 64 bf16 = 128 B = 8 granules (granule = 16 B)

typedef __bf16 bf16;
typedef __attribute__((ext_vector_type(8))) __bf16 bf16x8;
typedef __attribute__((ext_vector_type(4))) __bf16 bf16x4;
typedef __attribute__((ext_vector_type(4))) float floatx4;

__device__ inline void async16(const void* g, void* l) {
    __builtin_amdgcn_global_load_lds(
        (const __attribute__((address_space(1))) unsigned int*)g,
        (__attribute__((address_space(3))) unsigned int*)l, 16, 0, 0);
}

// Device-coherent (cross-XCD) scalar access to `partial`: relaxed atomics
// at AGENT scope compile to write-through / cache-bypassing global ops —
// NO buffer_wbl2 (the round-7 killer). Ordering to the completion counter
// is via the vmcnt(0) drain implicit in __syncthreads.
__device__ inline void store_coh(float* p, float v) {
    __hip_atomic_store(p, v, __ATOMIC_RELAXED, __HIP_MEMORY_SCOPE_AGENT);
}
__device__ inline float load_coh(const float* p) {
    return __hip_atomic_load(p, __ATOMIC_RELAXED, __HIP_MEMORY_SCOPE_AGENT);
}

// ---------------- K1: fused prep ----------------
// blocks [0, NCV)              : fp32->bf16 convert of W2 (1 MB only)
// block  NCV                   : mask dtype probe (plain write) + bcnt init
// blocks [NCV+1, NCV+1+4096)   : w1q[b][a] = dot(query[b,:], W1[a,:])
// blocks [NCV+1+4096, +32)     : per-batch mask compaction -> idx, cnt
#define NW8 (AD * DD / 8)
#define NCV (NW8 / 256)   // 128
__global__ void prep_kernel(const float* __restrict__ W2,
                            bf16* __restrict__ W2b,
                            const unsigned char* __restrict__ m8,
                            int* __restrict__ flag,
                            int* __restrict__ bcnt,
                            const float* __restrict__ query,
                            const float* __restrict__ W1,
                            float* __restrict__ w1q,
                            int* __restrict__ cnt,
                            int* __restrict__ idxb) {
    const int bid = blockIdx.x;
    if (bid < NCV) {
        int j = threadIdx.x + bid * 256;
        const float4* s4 = (const float4*)W2 + (size_t)j * 2;
        float4 x = s4[0], y = s4[1];
        bf16x8 o;
        o[0] = (bf16)x.x; o[1] = (bf16)x.y; o[2] = (bf16)x.z; o[3] = (bf16)x.w;
        o[4] = (bf16)y.x; o[5] = (bf16)y.y; o[6] = (bf16)y.z; o[7] = (bf16)y.w;
        *(bf16x8*)(W2b + (size_t)j * 8) = o;
    } else if (bid == NCV) {
        // probe first 64 KB of mask (16K entries; error prob ~2^-1500) and
        // PLAIN-write flag (no pre-zero needed); zero completion counters.
        const int t = threadIdx.x;
        __shared__ int s_any;
        if (t == 0) s_any = 0;
        if (t < 32) bcnt[t] = 0;
        __syncthreads();
        const uint4* m16 = (const uint4*)m8;
        unsigned pr = 0;
#pragma unroll
        for (int k = 0; k < 16; ++k) {
            uint4 x = m16[t + 256 * k];
            pr |= (x.x | x.y | x.z | x.w) & 0xFFFFFF00u;
        }
        if (pr) atomicOr(&s_any, 1);
        __syncthreads();
        if (t == 0) *flag = s_any;
    } else if (bid < NCV + 1 + 4096) {
        int id = bid - NCV - 1;            // 0..4095
        int b = id >> 7;
        int a = (id & 127) * 4 + (threadIdx.x >> 6);
        int lane = threadIdx.x & 63;
        const float4* q4 = (const float4*)(query + (size_t)b * DD) + lane * 2;
        const float4* w4 = (const float4*)(W1 + (size_t)a * DD) + lane * 2;
        float4 qa = q4[0], qb = q4[1];
        float4 wa = w4[0], wb = w4[1];
        float acc = qa.x * wa.x + qa.y * wa.y + qa.z * wa.z + qa.w * wa.w
                  + qb.x * wb.x + qb.y * wb.y + qb.z * wb.z + qb.w * wb.w;
#pragma unroll
        for (int off = 32; off > 0; off >>= 1) acc += __shfl_down(acc, off);
        if (lane == 0) w1q[(size_t)b * AD + a] = acc;
    } else {
        // ---- compaction: one block per batch ----
        const int b = bid - NCV - 1 - 4096;   // 0..31
        const int t = threadIdx.x;
        const int lane = t & 63, wid = t >> 6;
        __shared__ int s_base;
        __shared__ int wsum[4];
        __shared__ int s_bytes;
        if (t == 0) { s_base = 0; s_bytes = 0; }
        __syncthreads();
        {
            const unsigned* mu = (const unsigned*)m8;
            unsigned pr = (mu[t] | mu[t + 256]) & 0xFFFFFF00u;
            if (pr) atomicOr(&s_bytes, 1);
        }
        __syncthreads();
        const int bytes = s_bytes;
        const int* m32 = (const int*)m8;
#pragma unroll 1
        for (int c = 0; c < 8; ++c) {
            int s = c * 256 + t;
            int mv = bytes ? (int)m8[(size_t)b * SS + s]
                           : m32[(size_t)b * SS + s];
            unsigned long long ball = __ballot(mv != 0);
            int rank = __popcll(ball & ((1ull << lane) - 1ull));
            if (lane == 0) wsum[wid] = __popcll(ball);
            __syncthreads();
            int woff = s_base;
            for (int j = 0; j < wid; ++j) woff += wsum[j];
            if (mv) idxb[(size_t)b * SS + woff + rank] = s;
            __syncthreads();
            if (t == 0) s_base += wsum[0] + wsum[1] + wsum[2] + wsum[3];
            __syncthreads();
        }
        if (t == 0) cnt[b] = s_base;
    }
}

// ---------------- K2: gathered MFMA GEMM + tanh/v + FUSED softmax ---------
// Round-6 compute VERBATIM (gather gemm, <80 us verified, FETCH 37 MB).
// Fusion v2: partial stores are AGENT-scope relaxed atomic stores (write-
// through coherent, no wbl2); completion counter is a RELAXED device atomic
// after __syncthreads (whose implicit vmcnt(0) drain is the release); the
// last block per batch re-reads partial via AGENT-scope relaxed atomic
// loads (bypass stale caches) and runs the masked softmax inline.
__global__ __launch_bounds__(256, 3)
void gemm_scores_mfma(const float* __restrict__ keys,
                      const bf16* __restrict__ W2b,
                      const float* __restrict__ w1q,
                      const float* __restrict__ v,
                      const int* __restrict__ cnt,
                      const int* __restrict__ idxb,
                      float* __restrict__ partial,
                      const int* __restrict__ mask_i32,
                      const unsigned char* __restrict__ mask_u8,
                      const int* __restrict__ flag,
                      int* __restrict__ bcnt,
                      float* __restrict__ out) {
    __shared__ float a_lds[BM * BK];   // 32 KB fp32
    __shared__ bf16  b_lds[BN * BK];   // 16 KB bf16
    __shared__ int   idx_lds[BM];      // 512 B
    __shared__ float rmax[4], rsum[4];
    __shared__ int   s_last;

    const int t    = threadIdx.x;
    const int lane = t & 63;
    const int w    = t >> 6;
    const int ml   = lane & 15;
    const int kg   = lane >> 4;

    // grid decode: lin -> (keys-tile kt, a_tile) with lin&7 == kt&7 (XCD)
    const int lin    = blockIdx.x;
    const int x8     = lin & 7;
    const int hi     = lin >> 3;
    const int a_tile = hi & 3;
    const int kt     = x8 + ((hi >> 2) << 3);   // 0..511
    const int b      = kt >> 4;
    const int s0     = (kt & 15) * BM;
    const int a0     = a_tile * BN;

    const int cntb = cnt[b];
    if (s0 >= cntb) return;            // whole tile masked out -> no work

    const int m_off = (w & 1) * 64;
    const int n_off = (w >> 1) * 64;

    const float* Akeys = keys + (size_t)b * SS * DD;
    const bf16*  Bblk  = W2b + (size_t)a0 * DD;

    // stage the idx tile (clamped; cntb >= 1 here)
    if (t < BM) {
        int p = s0 + t;
        idx_lds[t] = idxb[(size_t)b * SS + (p < cntb ? p : cntb - 1)];
    }
    __syncthreads();

    // hoist the 8 per-thread A-row gathers (rows are chunk-invariant)
    int arow[8];
#pragma unroll
    for (int i = 0; i < 8; ++i) arow[i] = idx_lds[(t + 256 * i) >> 4];

    floatx4 acc[4][4];
#pragma unroll
    for (int mi = 0; mi < 4; ++mi)
#pragma unroll
        for (int ni = 0; ni < 4; ++ni)
            acc[mi][ni] = (floatx4)(0.f);

    const int NCHUNK = DD / BK;   // 8
    for (int c = 0; c < NCHUNK; ++c) {
        const int d0 = c * BK;
        __syncthreads();   // previous chunk's frag reads done
        // A: 2048 granules (16B = 4 fp32), 8 per thread, row-gathered
#pragma unroll
        for (int i = 0; i < 8; ++i) {
            int g = t + 256 * i;
            int r = g >> 4, cc = g & 15, cs = cc ^ (r & 15);
            async16(Akeys + (size_t)arow[i] * DD + d0 + cs * 4,
                    &a_lds[(256 * i + 64 * w) * 4]);
        }
        // B: 1024 granules (16B = 8 bf16), 4 per thread
#pragma unroll
        for (int i = 0; i < 4; ++i) {
            int g = t + 256 * i;
            int r = g >> 3, cc = g & 7, cs = cc ^ (r & 7);
            async16(Bblk + (size_t)r * DD + d0 + cs * 8,
                    &b_lds[(256 * i + 64 * w) * 8]);
        }
        __syncthreads();   // staging drained

#pragma unroll
        for (int ks = 0; ks < 2; ++ks) {
            bf16x8 af[4], bfr[4];
#pragma unroll
            for (int mi = 0; mi < 4; ++mi) {
                int R  = m_off + mi * 16 + ml;
                int gB = 8 * ks + 2 * kg;           // even
                float4 lo = *(const float4*)&a_lds[R * BK + ((gB    ) ^ (R & 15)) * 4];
                float4 hi4 = *(const float4*)&a_lds[R * BK + ((gB + 1) ^ (R & 15)) * 4];
                bf16x8 f;
                f[0] = (bf16)lo.x;  f[1] = (bf16)lo.y;
                f[2] = (bf16)lo.z;  f[3] = (bf16)lo.w;
                f[4] = (bf16)hi4.x; f[5] = (bf16)hi4.y;
                f[6] = (bf16)hi4.z; f[7] = (bf16)hi4.w;
                af[mi] = f;
            }
#pragma unroll
            for (int ni = 0; ni < 4; ++ni) {
                int R = n_off + ni * 16 + ml;
                int pos = (ks * 4 + kg) ^ (R & 7);
                bfr[ni] = *(const bf16x8*)&b_lds[R * BK + pos * 8];
            }
#pragma unroll
            for (int mi = 0; mi < 4; ++mi)
#pragma unroll
                for (int ni = 0; ni < 4; ++ni)
                    acc[mi][ni] = __builtin_amdgcn_mfma_f32_16x16x32_bf16(
                        af[mi], bfr[ni], acc[mi][ni], 0, 0, 0);
        }
    }

    // epilogue: tanh + v-weight; quad shuffle-reduce; coherent scatter
    // store to partial[(b, idx[row])*8 + a_tile*2 + n_half], rows < cntb.
    float w1qa[4], va[4];
#pragma unroll
    for (int ni = 0; ni < 4; ++ni) {
        int a = a0 + n_off + ni * 16 + ml;
        w1qa[ni] = w1q[(size_t)b * AD + a];
        va[ni]   = v[a];
    }
    const int slot = a_tile * 2 + (w >> 1);
#pragma unroll
    for (int mi = 0; mi < 4; ++mi) {
#pragma unroll
        for (int reg = 0; reg < 4; ++reg) {
            float p = 0.f;
#pragma unroll
            for (int ni = 0; ni < 4; ++ni) {
                float x = acc[mi][ni][reg] + w1qa[ni];
                float th = 1.f - 2.f / (1.f + __expf(2.f * x));
                p = fmaf(th, va[ni], p);
            }
            p += __shfl_xor(p, 1);
            p += __shfl_xor(p, 2);
            p += __shfl_xor(p, 4);
            p += __shfl_xor(p, 8);
            int row = m_off + mi * 16 + kg * 4 + reg;
            if (ml == 0 && s0 + row < cntb) {
                int os = idx_lds[row];
                store_coh(&partial[((size_t)b * SS + os) * 8 + slot], p);
            }
        }
    }

    // ---- fused completion (cheap): __syncthreads drains vmcnt(0) (all
    // waves' coherent stores acked) -> relaxed device atomic. NO wbl2.
    __syncthreads();
    if (t == 0) {
        const int nact = 4 * ((cntb + BM - 1) / BM);
        int old = __hip_atomic_fetch_add(&bcnt[b], 1, __ATOMIC_RELAXED,
                                         __HIP_MEMORY_SCOPE_AGENT);
        s_last = (old == nact - 1);
    }
    __syncthreads();
    if (!s_last) return;

    {
        const int wid = w;
        const int bytes = (*flag != 0);
        float sv[8]; int mv[8];
#pragma unroll
        for (int k = 0; k < 8; ++k) {
            int i = t + 256 * k;
            const float* p8 = partial + ((size_t)b * SS + i) * 8;
            float s = 0.f;
#pragma unroll
            for (int j = 0; j < 8; ++j) s += load_coh(p8 + j);
            sv[k] = s;
            mv[k] = bytes ? (int)mask_u8[(size_t)b * SS + i]
                          : mask_i32[(size_t)b * SS + i];
        }

        float mx = -INFINITY;
#pragma unroll
        for (int k = 0; k < 8; ++k) mx = fmaxf(mx, mv[k] ? sv[k] : -INFINITY);
#pragma unroll
        for (int off = 32; off > 0; off >>= 1) mx = fmaxf(mx, __shfl_xor(mx, off));
        if (lane == 0) rmax[wid] = mx;
        __syncthreads();
        mx = fmaxf(fmaxf(rmax[0], rmax[1]), fmaxf(rmax[2], rmax[3]));

        float ev[8]; float sum = 0.f;
#pragma unroll
        for (int k = 0; k < 8; ++k) {
            ev[k] = mv[k] ? __expf(sv[k] - mx) : 0.f;
            sum += ev[k];
        }
#pragma unroll
        for (int off = 32; off > 0; off >>= 1) sum += __shfl_xor(sum, off);
        if (lane == 0) rsum[wid] = sum;
        __syncthreads();
        sum = (rsum[0] + rsum[1]) + (rsum[2] + rsum[3]);
        float inv = 1.f / sum;
#pragma unroll
        for (int k = 0; k < 8; ++k)
            out[(size_t)b * SS + t + 256 * k] = ev[k] * inv;
    }
}

// ---------------- K2-fallback (round-0 verbatim, no gather) ---------------
#define FBK 32
#define FLDK (FBK + 8)
__global__ __launch_bounds__(256, 2)
void gemm_scores_fallback(const float* __restrict__ keys,
                          const float* __restrict__ W2,
                          const float* __restrict__ w1q,
                          const float* __restrict__ v,
                          float* __restrict__ partial) {
    __shared__ bf16 a_lds[BM][FLDK];
    __shared__ bf16 b_lds[BN][FLDK];
    __shared__ float s_red[BM];

    const int t    = threadIdx.x;
    const int lane = t & 63;
    const int w    = t >> 6;
    const int ml   = lane & 15;
    const int kg   = lane >> 4;
    const int b    = blockIdx.z;
    const int s0   = blockIdx.x * BM;
    const int a0   = blockIdx.y * BN;
    const int m_off = (w & 1) * 64;
    const int n_off = (w >> 1) * 64;

    const float* Ablk = keys + ((size_t)b * SS + s0) * DD;
    const float* Bblk = W2 + (size_t)a0 * DD;

    if (t < BM) s_red[t] = 0.f;

    floatx4 acc[4][4];
#pragma unroll
    for (int mi = 0; mi < 4; ++mi)
#pragma unroll
        for (int ni = 0; ni < 4; ++ni)
            acc[mi][ni] = (floatx4)(0.f);

    float4 ga[4], gb[4];
#pragma unroll
    for (int i = 0; i < 4; ++i) {
        int idx = t + 256 * i;
        int r = idx >> 3, c = idx & 7;
        ga[i] = *(const float4*)(Ablk + (size_t)r * DD + c * 4);
        gb[i] = *(const float4*)(Bblk + (size_t)r * DD + c * 4);
    }

    for (int chunk = 0; chunk < DD / FBK; ++chunk) {
        __syncthreads();
#pragma unroll
        for (int i = 0; i < 4; ++i) {
            int idx = t + 256 * i;
            int r = idx >> 3, c = idx & 7;
            bf16x4 pa, pb;
            pa[0] = (bf16)ga[i].x; pa[1] = (bf16)ga[i].y;
            pa[2] = (bf16)ga[i].z; pa[3] = (bf16)ga[i].w;
            pb[0] = (bf16)gb[i].x; pb[1] = (bf16)gb[i].y;
            pb[2] = (bf16)gb[i].z; pb[3] = (bf16)gb[i].w;
            *(bf16x4*)&a_lds[r][c * 4] = pa;
            *(bf16x4*)&b_lds[r][c * 4] = pb;
        }
        __syncthreads();
        if (chunk < DD / FBK - 1) {
            int d0 = (chunk + 1) * FBK;
#pragma unroll
            for (int i = 0; i < 4; ++i) {
                int idx = t + 256 * i;
                int r = idx >> 3, c = idx & 7;
                ga[i] = *(const float4*)(Ablk + (size_t)r * DD + d0 + c * 4);
                gb[i] = *(const float4*)(Bblk + (size_t)r * DD + d0 + c * 4);
            }
        }
        bf16x8 af[4], bfr[4];
#pragma unroll
        for (int mi = 0; mi < 4; ++mi)
            af[mi] = *(const bf16x8*)&a_lds[m_off + mi * 16 + ml][kg * 8];
#pragma unroll
        for (int ni = 0; ni < 4; ++ni)
            bfr[ni] = *(const bf16x8*)&b_lds[n_off + ni * 16 + ml][kg * 8];
#pragma unroll
        for (int mi = 0; mi < 4; ++mi)
#pragma unroll
            for (int ni = 0; ni < 4; ++ni)
                acc[mi][ni] = __builtin_amdgcn_mfma_f32_16x16x32_bf16(
                    af[mi], bfr[ni], acc[mi][ni], 0, 0, 0);
    }

    float w1qa[4], va[4];
#pragma unroll
    for (int ni = 0; ni < 4; ++ni) {
        int a = a0 + n_off + ni * 16 + ml;
        w1qa[ni] = w1q[(size_t)b * AD + a];
        va[ni]   = v[a];
    }
#pragma unroll
    for (int mi = 0; mi < 4; ++mi) {
#pragma unroll
        for (int reg = 0; reg < 4; ++reg) {
            float p = 0.f;
#pragma unroll
            for (int ni = 0; ni < 4; ++ni) {
                float x = acc[mi][ni][reg] + w1qa[ni];
                float th = 1.f - 2.f / (1.f + __expf(2.f * x));
                p = fmaf(th, va[ni], p);
            }
            p += __shfl_xor(p, 1);
            p += __shfl_xor(p, 2);
            p += __shfl_xor(p, 4);
            p += __shfl_xor(p, 8);
            if (ml == 0)
                atomicAdd(&s_red[m_off + mi * 16 + kg * 4 + reg], p);
        }
    }
    __syncthreads();
    if (t < BM)
        partial[(((size_t)b * SS) + s0 + t) * 8 + blockIdx.y * 2] = s_red[t];
}

// ---------------- K3: standalone softmax (fallback path only) -------------
__global__ void softmax_kernel(const float* __restrict__ partial,
                               const int* __restrict__ mask_i32,
                               const unsigned char* __restrict__ mask_u8,
                               const int* __restrict__ flag,
                               float* __restrict__ out) {
    const int b = blockIdx.x;
    const int t = threadIdx.x;
    __shared__ float rmax[4], rsum[4];
    const int wid = t >> 6, lane = t & 63;

    float sv[8]; int mv[8];
    const int bytes = (*flag != 0);
#pragma unroll
    for (int k = 0; k < 8; ++k) {
        int i = t + 256 * k;
        const float4* p4 = (const float4*)(partial + ((size_t)b * SS + i) * 8);
        float4 pa = p4[0], pb = p4[1];
        sv[k] = ((pa.x + pa.y) + (pa.z + pa.w)) + ((pb.x + pb.y) + (pb.z + pb.w));
        mv[k] = bytes ? (int)mask_u8[(size_t)b * SS + i]
                      : mask_i32[(size_t)b * SS + i];
    }

    float mx = -INFINITY;
#pragma unroll
    for (int k = 0; k < 8; ++k) mx = fmaxf(mx, mv[k] ? sv[k] : -INFINITY);
#pragma unroll
    for (int off = 32; off > 0; off >>= 1) mx = fmaxf(mx, __shfl_xor(mx, off));
    if (lane == 0) rmax[wid] = mx;
    __syncthreads();
    mx = fmaxf(fmaxf(rmax[0], rmax[1]), fmaxf(rmax[2], rmax[3]));

    float ev[8]; float sum = 0.f;
#pragma unroll
    for (int k = 0; k < 8; ++k) {
        ev[k] = mv[k] ? __expf(sv[k] - mx) : 0.f;
        sum += ev[k];
    }
#pragma unroll
    for (int off = 32; off > 0; off >>= 1) sum += __shfl_xor(sum, off);
    if (lane == 0) rsum[wid] = sum;
    __syncthreads();
    sum = (rsum[0] + rsum[1]) + (rsum[2] + rsum[3]);
    float inv = 1.f / sum;
#pragma unroll
    for (int k = 0; k < 8; ++k)
        out[(size_t)b * SS + t + 256 * k] = ev[k] * inv;
}

extern "C" void kernel_launch(void* const* d_in, const int* in_sizes, int n_in,
                              void* d_out, int out_size, void* d_ws, size_t ws_size,
                              hipStream_t stream) {
    const float* query = (const float*)d_in[0];
    const float* keys  = (const float*)d_in[1];
    const void*  mask  = d_in[2];
    const float* W1    = (const float*)d_in[3];
    const float* W2    = (const float*)d_in[4];
    const float* v     = (const float*)d_in[5];
    float* out = (float*)d_out;

    // ws layout (bytes):
    // [flag 4 @0 | bcnt[32] @64 | pad to 256][w1q 64K][partial 2M]
    // [W2b 0.5M][cnt 256][idx 256K]
    char* wsb = (char*)d_ws;
    int*   flag    = (int*)wsb;
    int*   bcnt    = (int*)(wsb + 64);
    float* w1q     = (float*)(wsb + 256);
    float* partial = (float*)(wsb + 256 + 65536);
    bf16*  W2b     = (bf16*)(wsb + 256 + 65536 + 2097152);
    int*   cnt     = (int*)(wsb + 256 + 65536 + 2097152 + 524288);
    int*   idxb    = (int*)(wsb + 256 + 65536 + 2097152 + 524288 + 256);
    size_t need = 256 + 65536 + 2097152 + 524288 + 256
                + (size_t)BB * SS * sizeof(int);

    if (ws_size >= need) {
        // 2 dispatches: prep (inits flag+bcnt itself), fused gemm+softmax
        prep_kernel<<<NCV + 1 + 4096 + 32, 256, 0, stream>>>(
            W2, W2b, (const unsigned char*)mask, flag, bcnt, query, W1, w1q,
            cnt, idxb);
        gemm_scores_mfma<<<(SS / BM) * (AD / BN) * BB, 256, 0, stream>>>(
            keys, W2b, w1q, v, cnt, idxb, partial,
            (const int*)mask, (const unsigned char*)mask, flag, bcnt, out);
    } else {
        hipMemsetAsync(partial, 0, (size_t)BB * SS * 8 * 4, stream);
        prep_kernel<<<NCV + 1 + 4096, 256, 0, stream>>>(
            W2, (bf16*)(wsb + 256 + 65536 + 2097152),
            (const unsigned char*)mask, flag, bcnt, query, W1, w1q,
            nullptr, nullptr);
        gemm_scores_fallback<<<dim3(SS / BM, AD / BN, BB), 256, 0, stream>>>(
            keys, W2, w1q, v, partial);
        softmax_kernel<<<BB, 256, 0, stream>>>(partial, (const int*)mask,
                                               (const unsigned char*)mask,
                                               flag, out);
    }
}

// Round 9
// 244.330 us; speedup vs baseline: 2.1293x; 1.0881x over previous
//
#include <hip/hip_runtime.h>
#include <math.h>

#define BB 32
#define SS 2048
#define DD 512
#define AD 512

#define BM 128
#define BN 128
#define BK 64    // K elems per chunk. A row: 64 fp32 = 256 B = 16 granules;
                 // B row: 64 bf16 = 128 B = 8 granules (granule = 16 B)

typedef __bf16 bf16;
typedef __attribute__((ext_vector_type(8))) __bf16 bf16x8;
typedef __attribute__((ext_vector_type(4))) __bf16 bf16x4;
typedef __attribute__((ext_vector_type(4))) float floatx4;

__device__ inline void async16(const void* g, void* l) {
    __builtin_amdgcn_global_load_lds(
        (const __attribute__((address_space(1))) unsigned int*)g,
        (__attribute__((address_space(3))) unsigned int*)l, 16, 0, 0);
}

// ---------------- K1: fused prep ----------------
// blocks [0, NCV)                  : fp32->bf16 convert of W2 (1 MB only)
// blocks [NCV, NCV+64)             : mask dtype probe -> flag (for softmax)
// blocks [NCV+64, NCV+64+4096)     : w1q[b][a] = dot(query[b,:], W1[a,:])
// blocks [NCV+64+4096, +32)        : per-batch mask compaction -> idx, cnt
#define NW8 (AD * DD / 8)
#define NCV (NW8 / 256)   // 128
__global__ void prep_kernel(const float* __restrict__ W2,
                            bf16* __restrict__ W2b,
                            const unsigned char* __restrict__ m8,
                            int* __restrict__ flag,
                            const float* __restrict__ query,
                            const float* __restrict__ W1,
                            float* __restrict__ w1q,
                            int* __restrict__ cnt,
                            int* __restrict__ idxb) {
    const int bid = blockIdx.x;
    if (bid < NCV) {
        int j = threadIdx.x + bid * 256;
        const float4* s4 = (const float4*)W2 + (size_t)j * 2;
        float4 x = s4[0], y = s4[1];
        bf16x8 o;
        o[0] = (bf16)x.x; o[1] = (bf16)x.y; o[2] = (bf16)x.z; o[3] = (bf16)x.w;
        o[4] = (bf16)y.x; o[5] = (bf16)y.y; o[6] = (bf16)y.z; o[7] = (bf16)y.w;
        *(bf16x8*)(W2b + (size_t)j * 8) = o;
    } else if (bid < NCV + 64) {
        int t = threadIdx.x + (bid - NCV) * 256;
        int any = 0;
        for (int i = t; i < BB * SS; i += 64 * 256)
            if ((i & 3) && m8[i]) any = 1;
        if (__any(any)) {
            if ((threadIdx.x & 63) == 0) atomicOr(flag, 1);
        }
    } else if (bid < NCV + 64 + 4096) {
        int id = bid - NCV - 64;           // 0..4095
        int b = id >> 7;
        int a = (id & 127) * 4 + (threadIdx.x >> 6);
        int lane = threadIdx.x & 63;
        const float4* q4 = (const float4*)(query + (size_t)b * DD) + lane * 2;
        const float4* w4 = (const float4*)(W1 + (size_t)a * DD) + lane * 2;
        float4 qa = q4[0], qb = q4[1];
        float4 wa = w4[0], wb = w4[1];
        float acc = qa.x * wa.x + qa.y * wa.y + qa.z * wa.z + qa.w * wa.w
                  + qb.x * wb.x + qb.y * wb.y + qb.z * wb.z + qb.w * wb.w;
#pragma unroll
        for (int off = 32; off > 0; off >>= 1) acc += __shfl_down(acc, off);
        if (lane == 0) w1q[(size_t)b * AD + a] = acc;
    } else {
        // ---- compaction: one block per batch ----
        const int b = bid - NCV - 64 - 4096;   // 0..31
        const int t = threadIdx.x;
        const int lane = t & 63, wid = t >> 6;
        __shared__ int s_base;
        __shared__ int wsum[4];
        __shared__ int s_bytes;
        if (t == 0) { s_base = 0; s_bytes = 0; }
        __syncthreads();
        // local dtype probe on first 2048 bytes (valid for either dtype):
        // i32 mask entries are 0/1 -> bytes %4!=0 all zero; u8 mask has
        // ~1024 nonzero bytes there -> decision error prob ~2^-1500.
        {
            const unsigned* mu = (const unsigned*)m8;
            unsigned pr = (mu[t] | mu[t + 256]) & 0xFFFFFF00u;
            if (pr) atomicOr(&s_bytes, 1);
        }
        __syncthreads();
        const int bytes = s_bytes;
        const int* m32 = (const int*)m8;
#pragma unroll 1
        for (int c = 0; c < 8; ++c) {
            int s = c * 256 + t;
            int mv = bytes ? (int)m8[(size_t)b * SS + s]
                           : m32[(size_t)b * SS + s];
            unsigned long long ball = __ballot(mv != 0);
            int rank = __popcll(ball & ((1ull << lane) - 1ull));
            if (lane == 0) wsum[wid] = __popcll(ball);
            __syncthreads();
            int woff = s_base;
            for (int j = 0; j < wid; ++j) woff += wsum[j];
            if (mv) idxb[(size_t)b * SS + woff + rank] = s;
            __syncthreads();
            if (t == 0) s_base += wsum[0] + wsum[1] + wsum[2] + wsum[3];
            __syncthreads();
        }
        if (t == 0) cnt[b] = s_base;
    }
}

// ---------------- K2: fp32-A async16 MFMA GEMM + tanh/v epilogue ----------
// Round-0 structure VERBATIM (90 us measured: BK=64, single-buffered,
// 2 barriers/chunk, XOR swizzle, 48KB -> 3 blocks/CU) + row-gather:
// only unmasked rows (compacted in idxb) are processed. Gather rides the
// per-lane GLOBAL address of async16 (LDS side stays linear). Blocks whose
// s-tile is beyond cnt[b] exit before any barrier. Epilogue scatters to
// the original s positions; masked rows keep garbage in partial, which
// softmax gates via mv==0 (same semantics as before).
__global__ __launch_bounds__(256, 3)
void gemm_scores_mfma(const float* __restrict__ keys,
                      const bf16* __restrict__ W2b,
                      const float* __restrict__ w1q,
                      const float* __restrict__ v,
                      const int* __restrict__ cnt,
                      const int* __restrict__ idxb,
                      float* __restrict__ partial) {
    __shared__ float a_lds[BM * BK];   // 32 KB fp32
    __shared__ bf16  b_lds[BN * BK];   // 16 KB bf16
    __shared__ int   idx_lds[BM];      // 512 B

    const int t    = threadIdx.x;
    const int lane = t & 63;
    const int w    = t >> 6;
    const int ml   = lane & 15;
    const int kg   = lane >> 4;

    // grid decode: lin -> (keys-tile kt, a_tile) with lin&7 == kt&7 (XCD)
    const int lin    = blockIdx.x;
    const int x8     = lin & 7;
    const int hi     = lin >> 3;
    const int a_tile = hi & 3;
    const int kt     = x8 + ((hi >> 2) << 3);   // 0..511
    const int b      = kt >> 4;
    const int s0     = (kt & 15) * BM;
    const int a0     = a_tile * BN;

    const int cntb = cnt[b];
    if (s0 >= cntb) return;            // whole tile masked out -> no work

    const int m_off = (w & 1) * 64;
    const int n_off = (w >> 1) * 64;

    const float* Akeys = keys + (size_t)b * SS * DD;
    const bf16*  Bblk  = W2b + (size_t)a0 * DD;

    // stage the idx tile (clamped; cntb >= 1 here)
    if (t < BM) {
        int p = s0 + t;
        idx_lds[t] = idxb[(size_t)b * SS + (p < cntb ? p : cntb - 1)];
    }
    __syncthreads();

    // hoist the 8 per-thread A-row gathers (rows are chunk-invariant)
    int arow[8];
#pragma unroll
    for (int i = 0; i < 8; ++i) arow[i] = idx_lds[(t + 256 * i) >> 4];

    floatx4 acc[4][4];
#pragma unroll
    for (int mi = 0; mi < 4; ++mi)
#pragma unroll
        for (int ni = 0; ni < 4; ++ni)
            acc[mi][ni] = (floatx4)(0.f);

    const int NCHUNK = DD / BK;   // 8
    for (int c = 0; c < NCHUNK; ++c) {
        const int d0 = c * BK;
        __syncthreads();   // previous chunk's frag reads done
        // A: 2048 granules (16B = 4 fp32), 8 per thread, row-gathered
#pragma unroll
        for (int i = 0; i < 8; ++i) {
            int g = t + 256 * i;
            int r = g >> 4, cc = g & 15, cs = cc ^ (r & 15);
            async16(Akeys + (size_t)arow[i] * DD + d0 + cs * 4,
                    &a_lds[(256 * i + 64 * w) * 4]);
        }
        // B: 1024 granules (16B = 8 bf16), 4 per thread
#pragma unroll
        for (int i = 0; i < 4; ++i) {
            int g = t + 256 * i;
            int r = g >> 3, cc = g & 7, cs = cc ^ (r & 7);
            async16(Bblk + (size_t)r * DD + d0 + cs * 8,
                    &b_lds[(256 * i + 64 * w) * 8]);
        }
        __syncthreads();   // staging drained

#pragma unroll
        for (int ks = 0; ks < 2; ++ks) {
            bf16x8 af[4], bfr[4];
#pragma unroll
            for (int mi = 0; mi < 4; ++mi) {
                int R  = m_off + mi * 16 + ml;
                int gB = 8 * ks + 2 * kg;           // even
                float4 lo = *(const float4*)&a_lds[R * BK + ((gB    ) ^ (R & 15)) * 4];
                float4 hi4 = *(const float4*)&a_lds[R * BK + ((gB + 1) ^ (R & 15)) * 4];
                bf16x8 f;
                f[0] = (bf16)lo.x;  f[1] = (bf16)lo.y;
                f[2] = (bf16)lo.z;  f[3] = (bf16)lo.w;
                f[4] = (bf16)hi4.x; f[5] = (bf16)hi4.y;
                f[6] = (bf16)hi4.z; f[7] = (bf16)hi4.w;
                af[mi] = f;
            }
#pragma unroll
            for (int ni = 0; ni < 4; ++ni) {
                int R = n_off + ni * 16 + ml;
                int pos = (ks * 4 + kg) ^ (R & 7);
                bfr[ni] = *(const bf16x8*)&b_lds[R * BK + pos * 8];
            }
#pragma unroll
            for (int mi = 0; mi < 4; ++mi)
#pragma unroll
                for (int ni = 0; ni < 4; ++ni)
                    acc[mi][ni] = __builtin_amdgcn_mfma_f32_16x16x32_bf16(
                        af[mi], bfr[ni], acc[mi][ni], 0, 0, 0);
        }
    }

    // epilogue: tanh + v-weight; quad shuffle-reduce over 64 a's; scatter
    // store to partial[(b, idx[row])*8 + a_tile*2 + n_half], rows < cntb.
    float w1qa[4], va[4];
#pragma unroll
    for (int ni = 0; ni < 4; ++ni) {
        int a = a0 + n_off + ni * 16 + ml;
        w1qa[ni] = w1q[(size_t)b * AD + a];
        va[ni]   = v[a];
    }
    const int slot = a_tile * 2 + (w >> 1);
#pragma unroll
    for (int mi = 0; mi < 4; ++mi) {
#pragma unroll
        for (int reg = 0; reg < 4; ++reg) {
            float p = 0.f;
#pragma unroll
            for (int ni = 0; ni < 4; ++ni) {
                float x = acc[mi][ni][reg] + w1qa[ni];
                float th = 1.f - 2.f / (1.f + __expf(2.f * x));
                p = fmaf(th, va[ni], p);
            }
            p += __shfl_xor(p, 1);
            p += __shfl_xor(p, 2);
            p += __shfl_xor(p, 4);
            p += __shfl_xor(p, 8);
            int row = m_off + mi * 16 + kg * 4 + reg;
            if (ml == 0 && s0 + row < cntb) {
                int os = idx_lds[row];
                partial[((size_t)b * SS + os) * 8 + slot] = p;
            }
        }
    }
}

// ---------------- K2-fallback (round-0 verbatim, no gather) ---------------
#define FBK 32
#define FLDK (FBK + 8)
__global__ __launch_bounds__(256, 2)
void gemm_scores_fallback(const float* __restrict__ keys,
                          const float* __restrict__ W2,
                          const float* __restrict__ w1q,
                          const float* __restrict__ v,
                          float* __restrict__ partial) {
    __shared__ bf16 a_lds[BM][FLDK];
    __shared__ bf16 b_lds[BN][FLDK];
    __shared__ float s_red[BM];

    const int t    = threadIdx.x;
    const int lane = t & 63;
    const int w    = t >> 6;
    const int ml   = lane & 15;
    const int kg   = lane >> 4;
    const int b    = blockIdx.z;
    const int s0   = blockIdx.x * BM;
    const int a0   = blockIdx.y * BN;
    const int m_off = (w & 1) * 64;
    const int n_off = (w >> 1) * 64;

    const float* Ablk = keys + ((size_t)b * SS + s0) * DD;
    const float* Bblk = W2 + (size_t)a0 * DD;

    if (t < BM) s_red[t] = 0.f;

    floatx4 acc[4][4];
#pragma unroll
    for (int mi = 0; mi < 4; ++mi)
#pragma unroll
        for (int ni = 0; ni < 4; ++ni)
            acc[mi][ni] = (floatx4)(0.f);

    float4 ga[4], gb[4];
#pragma unroll
    for (int i = 0; i < 4; ++i) {
        int idx = t + 256 * i;
        int r = idx >> 3, c = idx & 7;
        ga[i] = *(const float4*)(Ablk + (size_t)r * DD + c * 4);
        gb[i] = *(const float4*)(Bblk + (size_t)r * DD + c * 4);
    }

    for (int chunk = 0; chunk < DD / FBK; ++chunk) {
        __syncthreads();
#pragma unroll
        for (int i = 0; i < 4; ++i) {
            int idx = t + 256 * i;
            int r = idx >> 3, c = idx & 7;
            bf16x4 pa, pb;
            pa[0] = (bf16)ga[i].x; pa[1] = (bf16)ga[i].y;
            pa[2] = (bf16)ga[i].z; pa[3] = (bf16)ga[i].w;
            pb[0] = (bf16)gb[i].x; pb[1] = (bf16)gb[i].y;
            pb[2] = (bf16)gb[i].z; pb[3] = (bf16)gb[i].w;
            *(bf16x4*)&a_lds[r][c * 4] = pa;
            *(bf16x4*)&b_lds[r][c * 4] = pb;
        }
        __syncthreads();
        if (chunk < DD / FBK - 1) {
            int d0 = (chunk + 1) * FBK;
#pragma unroll
            for (int i = 0; i < 4; ++i) {
                int idx = t + 256 * i;
                int r = idx >> 3, c = idx & 7;
                ga[i] = *(const float4*)(Ablk + (size_t)r * DD + d0 + c * 4);
                gb[i] = *(const float4*)(Bblk + (size_t)r * DD + d0 + c * 4);
            }
        }
        bf16x8 af[4], bfr[4];
#pragma unroll
        for (int mi = 0; mi < 4; ++mi)
            af[mi] = *(const bf16x8*)&a_lds[m_off + mi * 16 + ml][kg * 8];
#pragma unroll
        for (int ni = 0; ni < 4; ++ni)
            bfr[ni] = *(const bf16x8*)&b_lds[n_off + ni * 16 + ml][kg * 8];
#pragma unroll
        for (int mi = 0; mi < 4; ++mi)
#pragma unroll
            for (int ni = 0; ni < 4; ++ni)
                acc[mi][ni] = __builtin_amdgcn_mfma_f32_16x16x32_bf16(
                    af[mi], bfr[ni], acc[mi][ni], 0, 0, 0);
    }

    float w1qa[4], va[4];
#pragma unroll
    for (int ni = 0; ni < 4; ++ni) {
        int a = a0 + n_off + ni * 16 + ml;
        w1qa[ni] = w1q[(size_t)b * AD + a];
        va[ni]   = v[a];
    }
#pragma unroll
    for (int mi = 0; mi < 4; ++mi) {
#pragma unroll
        for (int reg = 0; reg < 4; ++reg) {
            float p = 0.f;
#pragma unroll
            for (int ni = 0; ni < 4; ++ni) {
                float x = acc[mi][ni][reg] + w1qa[ni];
                float th = 1.f - 2.f / (1.f + __expf(2.f * x));
                p = fmaf(th, va[ni], p);
            }
            p += __shfl_xor(p, 1);
            p += __shfl_xor(p, 2);
            p += __shfl_xor(p, 4);
            p += __shfl_xor(p, 8);
            if (ml == 0)
                atomicAdd(&s_red[m_off + mi * 16 + kg * 4 + reg], p);
        }
    }
    __syncthreads();
    if (t < BM)
        partial[(((size_t)b * SS) + s0 + t) * 8 + blockIdx.y * 2] = s_red[t];
}

// ---------------- K3: combine 8 partials + masked softmax over s ----------
__global__ void softmax_kernel(const float* __restrict__ partial,
                               const int* __restrict__ mask_i32,
                               const unsigned char* __restrict__ mask_u8,
                               const int* __restrict__ flag,
                               float* __restrict__ out) {
    const int b = blockIdx.x;
    const int t = threadIdx.x;
    __shared__ float rmax[4], rsum[4];
    const int wid = t >> 6, lane = t & 63;

    float sv[8]; int mv[8];
    const int bytes = (*flag != 0);
#pragma unroll
    for (int k = 0; k < 8; ++k) {
        int i = t + 256 * k;
        const float4* p4 = (const float4*)(partial + ((size_t)b * SS + i) * 8);
        float4 pa = p4[0], pb = p4[1];
        sv[k] = ((pa.x + pa.y) + (pa.z + pa.w)) + ((pb.x + pb.y) + (pb.z + pb.w));
        mv[k] = bytes ? (int)mask_u8[(size_t)b * SS + i]
                      : mask_i32[(size_t)b * SS + i];
    }

    float mx = -INFINITY;
#pragma unroll
    for (int k = 0; k < 8; ++k) mx = fmaxf(mx, mv[k] ? sv[k] : -INFINITY);
#pragma unroll
    for (int off = 32; off > 0; off >>= 1) mx = fmaxf(mx, __shfl_xor(mx, off));
    if (lane == 0) rmax[wid] = mx;
    __syncthreads();
    mx = fmaxf(fmaxf(rmax[0], rmax[1]), fmaxf(rmax[2], rmax[3]));

    float ev[8]; float sum = 0.f;
#pragma unroll
    for (int k = 0; k < 8; ++k) {
        ev[k] = mv[k] ? __expf(sv[k] - mx) : 0.f;
        sum += ev[k];
    }
#pragma unroll
    for (int off = 32; off > 0; off >>= 1) sum += __shfl_xor(sum, off);
    if (lane == 0) rsum[wid] = sum;
    __syncthreads();
    sum = (rsum[0] + rsum[1]) + (rsum[2] + rsum[3]);
    float inv = 1.f / sum;
#pragma unroll
    for (int k = 0; k < 8; ++k)
        out[(size_t)b * SS + t + 256 * k] = ev[k] * inv;
}

extern "C" void kernel_launch(void* const* d_in, const int* in_sizes, int n_in,
                              void* d_out, int out_size, void* d_ws, size_t ws_size,
                              hipStream_t stream) {
    const float* query = (const float*)d_in[0];
    const float* keys  = (const float*)d_in[1];
    const void*  mask  = d_in[2];
    const float* W1    = (const float*)d_in[3];
    const float* W2    = (const float*)d_in[4];
    const float* v     = (const float*)d_in[5];
    float* out = (float*)d_out;

    // ws layout (bytes):
    // [flag 256][w1q 64K][partial 2M][W2b 0.5M][cnt 256][idx 256K]
    char* wsb = (char*)d_ws;
    int*   flag    = (int*)wsb;
    float* w1q     = (float*)(wsb + 256);
    float* partial = (float*)(wsb + 256 + 65536);
    bf16*  W2b     = (bf16*)(wsb + 256 + 65536 + 2097152);
    int*   cnt     = (int*)(wsb + 256 + 65536 + 2097152 + 524288);
    int*   idxb    = (int*)(wsb + 256 + 65536 + 2097152 + 524288 + 256);
    size_t need = 256 + 65536 + 2097152 + 524288 + 256
                + (size_t)BB * SS * sizeof(int);

    hipMemsetAsync(flag, 0, 4, stream);
    if (ws_size >= need) {
        prep_kernel<<<NCV + 64 + 4096 + 32, 256, 0, stream>>>(
            W2, W2b, (const unsigned char*)mask, flag, query, W1, w1q,
            cnt, idxb);
        gemm_scores_mfma<<<(SS / BM) * (AD / BN) * BB, 256, 0, stream>>>(
            keys, W2b, w1q, v, cnt, idxb, partial);
    } else {
        hipMemsetAsync(partial, 0, (size_t)BB * SS * 8 * 4, stream);
        prep_kernel<<<NCV + 64 + 4096, 256, 0, stream>>>(
            W2, (bf16*)(wsb + 256 + 65536 + 2097152),
            (const unsigned char*)mask, flag, query, W1, w1q,
            nullptr, nullptr);
        gemm_scores_fallback<<<dim3(SS / BM, AD / BN, BB), 256, 0, stream>>>(
            keys, W2, w1q, v, partial);
    }
    softmax_kernel<<<BB, 256, 0, stream>>>(partial, (const int*)mask,
                                           (const unsigned char*)mask, flag, out);
}